// Round 14
// baseline (1934.619 us; speedup 1.0000x reference)
//
#include <hip/hip_runtime.h>
#include <cstddef>
#include <cstdint>

// K-means (Lloyd, 10 fixed iters): N=1024 pts, K=64 centroids, D=98304.
// d_in[0]=x f32[1024*98304], d_in[1]=centroid f32[64*98304]
// d_out = concat(final state [64*98304] f32, last choice [1024] as f32)
//
// Round 14: (a) gbuild pipeline deepened: 3 LDS buffers (96KB, 1 block/CU),
// 2-deep prefetch, counted vmcnt(16/8/0) -- round 13's cycle model showed
// ~1000cy/chunk exposed HBM latency with the 1-deep 2-buffer scheme;
// (b) launch-count trim: c2up folded into assign (identical serial order,
// empty-k via persisted global c2), choice_out into sort2, tlast-init into
// dot0. Everything else byte-identical to round 13 (absmax 0.0).

#define N_PTS  1024
#define K_C    64
#define D_DIM  98304
#define ITERS  10
#define SPLITD 64          // init dot kernel split (1536 dims/seg)
#define NCHK   96          // D/1024
#define CCHK   12          // D/8192
#define NGRP   16          // gbuild seg-half groups
#define SHW    512         // shorts per seg-half
#define NCHT   192         // gbuild chunks per block
#define NPAIR  36          // 8x8 upper-triangle 128-tiles
#define GT     128
#define GDC    32          // dims per K-chunk

typedef __attribute__((ext_vector_type(8))) short bf16x8;
typedef __attribute__((ext_vector_type(8))) unsigned short ushort8;
typedef __attribute__((ext_vector_type(4))) float f32x4;

__device__ __forceinline__ unsigned short f2bf(float x) {   // RNE f32->bf16
    unsigned u = __float_as_uint(x);
    u = (u + 0x7FFFu + ((u >> 16) & 1u)) >> 16;
    return (unsigned short)u;
}
__device__ __forceinline__ float bf2f(unsigned short b) {
    return __uint_as_float((unsigned)b << 16);
}
__device__ __forceinline__ void cvt2(float x, unsigned short& h, unsigned short& l) {
    h = f2bf(x);
    l = f2bf(x - bf2f(h));
}

__device__ __forceinline__ void gload_lds16(const unsigned short* g, char* l) {
    __builtin_amdgcn_global_load_lds(
        (const __attribute__((address_space(1))) unsigned int*)g,
        (__attribute__((address_space(3))) unsigned int*)l, 16, 0, 0);
}

__device__ __forceinline__ float block_sum256(float s) {
    #pragma unroll
    for (int o = 32; o; o >>= 1) s += __shfl_down(s, o);
    __shared__ float red[4];
    int lane = threadIdx.x & 63, w = threadIdx.x >> 6;
    if (lane == 0) red[w] = s;
    __syncthreads();
    return red[0] + red[1] + red[2] + red[3];
}

// ---------------- convert rows fp32 -> bf16 hi/lo planes + sumsq partials ----------------
__global__ __launch_bounds__(256) void convert_kernel(const float* __restrict__ A,
                                                      unsigned short* __restrict__ Ph,
                                                      unsigned short* __restrict__ Pl,
                                                      float* __restrict__ sq_part) {
    const int n = blockIdx.x, j = blockIdx.y;
    const size_t base = (size_t)n * D_DIM + (size_t)j * 8192;
    const int t = threadIdx.x;
    float ss = 0.f;
    #pragma unroll
    for (int i = 0; i < 4; ++i) {
        size_t e = base + (size_t)i * 2048 + t * 8;
        float4 a = *reinterpret_cast<const float4*>(A + e);
        float4 b = *reinterpret_cast<const float4*>(A + e + 4);
        ss += a.x*a.x + a.y*a.y + a.z*a.z + a.w*a.w;
        ss += b.x*b.x + b.y*b.y + b.z*b.z + b.w*b.w;
        ushort4 h0, l0, h1, l1;
        cvt2(a.x, h0.x, l0.x); cvt2(a.y, h0.y, l0.y);
        cvt2(a.z, h0.z, l0.z); cvt2(a.w, h0.w, l0.w);
        cvt2(b.x, h1.x, l1.x); cvt2(b.y, h1.y, l1.y);
        cvt2(b.z, h1.z, l1.z); cvt2(b.w, h1.w, l1.w);
        *reinterpret_cast<ushort4*>(Ph + e)     = h0;
        *reinterpret_cast<ushort4*>(Ph + e + 4) = h1;
        *reinterpret_cast<ushort4*>(Pl + e)     = l0;
        *reinterpret_cast<ushort4*>(Pl + e + 4) = l1;
    }
    ss = block_sum256(ss);
    if (t == 0) sq_part[n * CCHK + j] = ss;
}

__global__ __launch_bounds__(256) void reduce_sq_kernel(const float* __restrict__ sq_part,
                                                        float* __restrict__ out, int rows) {
    int n = blockIdx.x * 256 + threadIdx.x;
    if (n >= rows) return;
    float s = 0.f;
    #pragma unroll
    for (int j = 0; j < CCHK; ++j) s += sq_part[n * CCHK + j];
    out[n] = s;
}

// ---------------- init dot vs C0: gbuild-style async dbuf engine ----------------
__global__ __launch_bounds__(256, 2) void mfma_dot2_kernel(const unsigned short* __restrict__ Xh,
                                                           const unsigned short* __restrict__ Xl,
                                                           const unsigned short* __restrict__ Sh,
                                                           const unsigned short* __restrict__ Sl,
                                                           float* __restrict__ partial) {
    __shared__ alignas(16) char L[49152];           // [buf][A 16K | B 8K]

    const int seg = blockIdx.x, nblk = blockIdx.y;
    const int t = threadIdx.x;
    const int wid = t >> 6, lane = t & 63;
    const int d_begin = seg * (D_DIM / SPLITD);     // seg * 1536
    const int NCH = (D_DIM / SPLITD) / GDC;         // 48

    const int isA = (wid < 2) ? 1 : 0;
    const int nj = isA ? 8 : 4;
    const int i0 = isA ? (wid & 1) * 8 : (wid & 1) * 4;
    const int tileoff = isA ? 0 : 16384;
    const int rowbase = isA ? nblk * 128 : 0;
    const int lw = (lane & 7) ^ (lane >> 3);
    const unsigned short* plane = isA ? ((lw & 4) ? Xl : Xh)
                                      : ((lw & 4) ? Sl : Sh);
    const unsigned short* gbase[8];
    #pragma unroll
    for (int j = 0; j < 8; ++j)
        gbase[j] = plane + (size_t)(rowbase + (i0 + j) * 8 + (lane >> 3)) * D_DIM + (lw & 3) * 8;

    const int sh = (lane >> 4) ^ (lane & 7);
    const int sl = (4 + (lane >> 4)) ^ (lane & 7);
    const int ra0 = (wid * 32 + (lane & 15)) * 128;
    const int rb0 = 16384 + (lane & 15) * 128;

    f32x4 acc[2][4];
    #pragma unroll
    for (int i = 0; i < 2; ++i)
        #pragma unroll
        for (int j = 0; j < 4; ++j) acc[i][j] = f32x4{0.f, 0.f, 0.f, 0.f};

    auto issue = [&](int idx) {
        const int d0 = d_begin + idx * GDC;
        char* dst = L + (idx & 1) * 24576 + tileoff + i0 * 1024;
        for (int j = 0; j < nj; ++j)
            gload_lds16(gbase[j] + d0, dst + j * 1024);
    };

    issue(0);
    for (int idx = 0; idx < NCH; ++idx) {
        if (idx + 1 < NCH) {
            issue(idx + 1);
            if (isA) asm volatile("s_waitcnt vmcnt(8)" ::: "memory");
            else     asm volatile("s_waitcnt vmcnt(4)" ::: "memory");
        } else {
            asm volatile("s_waitcnt vmcnt(0)" ::: "memory");
        }
        __builtin_amdgcn_s_barrier();
        __builtin_amdgcn_sched_barrier(0);
        const char* base = L + (idx & 1) * 24576;
        bf16x8 ah[2], al[2];
        #pragma unroll
        for (int fi = 0; fi < 2; ++fi) {
            ah[fi] = *reinterpret_cast<const bf16x8*>(base + ra0 + fi * 2048 + sh * 16);
            al[fi] = *reinterpret_cast<const bf16x8*>(base + ra0 + fi * 2048 + sl * 16);
        }
        #pragma unroll
        for (int fj = 0; fj < 4; ++fj) {
            bf16x8 bh = *reinterpret_cast<const bf16x8*>(base + rb0 + fj * 2048 + sh * 16);
            bf16x8 bl = *reinterpret_cast<const bf16x8*>(base + rb0 + fj * 2048 + sl * 16);
            #pragma unroll
            for (int fi = 0; fi < 2; ++fi) {
                acc[fi][fj] = __builtin_amdgcn_mfma_f32_16x16x32_bf16(ah[fi], bh, acc[fi][fj], 0, 0, 0);
                acc[fi][fj] = __builtin_amdgcn_mfma_f32_16x16x32_bf16(ah[fi], bl, acc[fi][fj], 0, 0, 0);
                acc[fi][fj] = __builtin_amdgcn_mfma_f32_16x16x32_bf16(al[fi], bh, acc[fi][fj], 0, 0, 0);
            }
        }
        __builtin_amdgcn_sched_barrier(0);
        __builtin_amdgcn_s_barrier();
    }

    #pragma unroll
    for (int fi = 0; fi < 2; ++fi)
        #pragma unroll
        for (int fj = 0; fj < 4; ++fj)
            #pragma unroll
            for (int r = 0; r < 4; ++r) {
                int n = nblk * 128 + wid * 32 + fi * 16 + (lane >> 4) * 4 + r;
                int col = fj * 16 + (lane & 15);
                partial[((size_t)seg * N_PTS + n) * K_C + col] = acc[fi][fj][r];
            }
}

__global__ __launch_bounds__(256) void reduce_dot_kernel(const float* __restrict__ partial,
                                                         float* __restrict__ dot) {
    int i = blockIdx.x * 256 + threadIdx.x;
    float s = 0.f;
    #pragma unroll 8
    for (int p = 0; p < SPLITD; ++p) s += partial[(size_t)p * N_PTS * K_C + i];
    dot[i] = s;
}

__global__ __launch_bounds__(256) void argmin_n_kernel(const float* __restrict__ dot,
                                                       const float* __restrict__ x2,
                                                       int* __restrict__ choice_pts) {
    int k = blockIdx.x;
    float best = 3.4e38f; int bi = N_PTS;
    for (int n = threadIdx.x; n < N_PTS; n += 256) {
        float v = fmaf(-2.f, dot[n * K_C + k], x2[n]);
        if (v < best || (v == best && n < bi)) { best = v; bi = n; }
    }
    #pragma unroll
    for (int off = 32; off; off >>= 1) {
        float v2 = __shfl_down(best, off);
        int   i2 = __shfl_down(bi, off);
        if (v2 < best || (v2 == best && i2 < bi)) { best = v2; bi = i2; }
    }
    __shared__ float bv[4]; __shared__ int bix[4];
    int lane = threadIdx.x & 63, wid = threadIdx.x >> 6;
    if (lane == 0) { bv[wid] = best; bix[wid] = bi; }
    __syncthreads();
    if (threadIdx.x == 0) {
        for (int w = 1; w < 4; ++w)
            if (bv[w] < best || (bv[w] == best && bix[w] < bi)) { best = bv[w]; bi = bix[w]; }
        choice_pts[k] = bi;
    }
}

// ---------------- gather snapped centroids (exact fp32) ----------------
__global__ __launch_bounds__(256) void gather_kernel(const float* __restrict__ X,
                                                     const int* __restrict__ choice_pts,
                                                     float* __restrict__ state) {
    int k = blockIdx.x;
    int c = choice_pts[k];
    size_t d = (size_t)blockIdx.y * 1024 + threadIdx.x * 4;
    float4 v = *reinterpret_cast<const float4*>(X + (size_t)c * D_DIM + d);
    *reinterpret_cast<float4*>(state + (size_t)k * D_DIM + d) = v;
}

// ---------------- G = X.X^T: 3-buffer async staging, 2-deep prefetch ----------------
// 576 blocks; id=(g%8)+8*(p+36*(g/8)) keeps all 36 pairs of a group on one
// XCD. 96KB LDS: 3 x {A 16K | B 16K}. Steady state: chunks i+1, i+2 in
// flight (16 loads/wave outstanding) while chunk i computes; vmcnt(16)
// waits only the oldest 8 (chunk i). Buf (i+2)%3 reuse is safe: last read
// during compute(i-1), whose trailing barrier precedes iter i's issue.
// Staging/swizzle byte-identical to rounds 9-13 (absmax 0.0, 0 conflicts).
__global__ __launch_bounds__(256) void gbuild_kernel(const unsigned short* __restrict__ Xh,
                                                     const unsigned short* __restrict__ Xl,
                                                     float* __restrict__ Gpart) {
    __shared__ alignas(16) char L[98304];           // 3 bufs x (A 16K | B 16K)

    const int id = blockIdx.x;
    const int xr = id & 7, q = id >> 3;
    const int p = q % NPAIR;
    const int g = ((q / NPAIR) << 3) + xr;          // 0..15
    int bi = 0, rem = p, rl = 8;
    while (rem >= rl) { rem -= rl; --rl; ++bi; }
    const int bj = bi + rem;

    const int t = threadIdx.x;
    const int wid = t >> 6, lane = t & 63;
    const int wr = wid >> 1, wc = wid & 1;

    const int isA = (wid < 2) ? 1 : 0;
    const int i0 = (wid & 1) * 8;
    const int tileoff = isA ? 0 : 16384;
    const int rowbase = (isA ? bi : bj) * GT;
    const int lw = (lane & 7) ^ (lane >> 3);
    const unsigned short* plane = (lw & 4) ? Xl : Xh;
    const unsigned short* gbase[8];
    #pragma unroll
    for (int j = 0; j < 8; ++j)
        gbase[j] = plane + (size_t)(rowbase + (i0 + j) * 8 + (lane >> 3)) * D_DIM + (lw & 3) * 8;

    const int sh = (lane >> 4) ^ (lane & 7);
    const int sl = (4 + (lane >> 4)) ^ (lane & 7);
    const int ra0 = (wr * 64 + (lane & 15)) * 128;
    const int rb0 = 16384 + (wc * 64 + (lane & 15)) * 128;

    f32x4 acc[4][4];
    #pragma unroll
    for (int i = 0; i < 4; ++i)
        #pragma unroll
        for (int j = 0; j < 4; ++j) acc[i][j] = f32x4{0.f, 0.f, 0.f, 0.f};

    auto issue = [&](int idx) {
        const int d0 = (g + ((idx >> 4) << 4)) * SHW + (idx & 15) * GDC;
        char* dst = L + (idx % 3) * 32768 + tileoff + i0 * 1024;
        #pragma unroll
        for (int j = 0; j < 8; ++j)
            gload_lds16(gbase[j] + d0, dst + j * 1024);
    };

    issue(0);
    issue(1);
    for (int idx = 0; idx < NCHT; ++idx) {
        if (idx + 2 < NCHT) {
            issue(idx + 2);
            asm volatile("s_waitcnt vmcnt(16)" ::: "memory");   // chunk idx landed
        } else if (idx + 1 < NCHT) {
            asm volatile("s_waitcnt vmcnt(8)" ::: "memory");
        } else {
            asm volatile("s_waitcnt vmcnt(0)" ::: "memory");
        }
        __builtin_amdgcn_s_barrier();
        __builtin_amdgcn_sched_barrier(0);
        const char* base = L + (idx % 3) * 32768;
        bf16x8 ah[4], al[4];
        #pragma unroll
        for (int fi = 0; fi < 4; ++fi) {
            ah[fi] = *reinterpret_cast<const bf16x8*>(base + ra0 + fi * 2048 + sh * 16);
            al[fi] = *reinterpret_cast<const bf16x8*>(base + ra0 + fi * 2048 + sl * 16);
        }
        #pragma unroll
        for (int fj = 0; fj < 4; ++fj) {
            bf16x8 bh = *reinterpret_cast<const bf16x8*>(base + rb0 + fj * 2048 + sh * 16);
            bf16x8 bl = *reinterpret_cast<const bf16x8*>(base + rb0 + fj * 2048 + sl * 16);
            #pragma unroll
            for (int fi = 0; fi < 4; ++fi) {
                acc[fi][fj] = __builtin_amdgcn_mfma_f32_16x16x32_bf16(ah[fi], bh, acc[fi][fj], 0, 0, 0);
                acc[fi][fj] = __builtin_amdgcn_mfma_f32_16x16x32_bf16(ah[fi], bl, acc[fi][fj], 0, 0, 0);
                acc[fi][fj] = __builtin_amdgcn_mfma_f32_16x16x32_bf16(al[fi], bh, acc[fi][fj], 0, 0, 0);
            }
        }
        __builtin_amdgcn_sched_barrier(0);
        __builtin_amdgcn_s_barrier();
    }

    float* gp = Gpart + ((size_t)g * NPAIR + p) * (GT * GT);
    #pragma unroll
    for (int fi = 0; fi < 4; ++fi)
        #pragma unroll
        for (int fj = 0; fj < 4; ++fj)
            #pragma unroll
            for (int r2 = 0; r2 < 4; ++r2) {
                int row = wr * 64 + fi * 16 + (lane >> 4) * 4 + r2;
                int col = wc * 64 + fj * 16 + (lane & 15);
                gp[row * GT + col] = acc[fi][fj][r2];
            }
}

// ---------------- reduce G partials over groups + mirror to lower triangle ----------------
__global__ __launch_bounds__(256) void reduce_g_kernel(const float* __restrict__ Gpart,
                                                       float* __restrict__ G) {
    const int p = blockIdx.x, blk = blockIdx.y;     // grid (NPAIR, 16)
    int bi = 0, rem = p, rl = 8;
    while (rem >= rl) { rem -= rl; --rl; ++bi; }
    const int bj = bi + rem;
    const int e0 = blk * 1024 + threadIdx.x * 4;
    float sx = 0.f, sy = 0.f, sz = 0.f, sw = 0.f;
    #pragma unroll 8
    for (int g = 0; g < NGRP; ++g) {
        const float4 v = *reinterpret_cast<const float4*>(
            Gpart + ((size_t)g * NPAIR + p) * (GT * GT) + e0);
        sx += v.x; sy += v.y; sz += v.z; sw += v.w;
    }
    const int row = e0 >> 7, col = e0 & 127;
    const int gi = bi * GT + row, gj = bj * GT + col;
    float4 o = {sx, sy, sz, sw};
    *reinterpret_cast<float4*>(&G[(size_t)gi * N_PTS + gj]) = o;
    if (bi != bj) {                                 // mirror (single writer per elem)
        G[(size_t)(gj + 0) * N_PTS + gi] = sx;
        G[(size_t)(gj + 1) * N_PTS + gi] = sy;
        G[(size_t)(gj + 2) * N_PTS + gi] = sz;
        G[(size_t)(gj + 3) * N_PTS + gi] = sw;
    }
}

// ---------------- dot0 + tlast init ----------------
__global__ __launch_bounds__(256) void dot0_kernel(const float* __restrict__ G,
                                                   const int* __restrict__ cpts,
                                                   const float* __restrict__ x2,
                                                   float* __restrict__ dot,
                                                   float* __restrict__ c2,
                                                   int* __restrict__ tlast) {
    int g = blockIdx.x * 256 + threadIdx.x;
    int n = g >> 6, k = g & 63;
    dot[g] = G[(size_t)n * N_PTS + cpts[k]];
    if (g < K_C) { c2[g] = x2[cpts[g]]; tlast[g] = -1; }
}

// ---------------- assign (+ folded c2 recompute, == c2up serial order) ----------------
// it0=1: use global c2 (from dot0). it0=0: each block recomputes c2[k] from
// dotg over members in ascending slot order (identical to c2up); empty k
// reads stale global c2; block 0 persists fresh values for future empties.
__global__ __launch_bounds__(256) void assign_g2_kernel(const float* __restrict__ dotg,
                                                        float* __restrict__ c2g,
                                                        const int* __restrict__ order,
                                                        const int* __restrict__ cstart,
                                                        int it0,
                                                        int* __restrict__ choice_it) {
    __shared__ float c2s[K_C];
    __shared__ int cst[K_C + 1];
    __shared__ int ord[N_PTS];
    int t = threadIdx.x;
    if (it0) {
        if (t < K_C) c2s[t] = c2g[t];
        __syncthreads();
    } else {
        #pragma unroll
        for (int i = 0; i < 4; ++i) ord[t + 256 * i] = order[t + 256 * i];
        if (t <= K_C) cst[t] = cstart[t];
        __syncthreads();
        if (t < K_C) {
            int b = cst[t], e = cst[t + 1];
            if (b == e) {
                c2s[t] = c2g[t];                      // empty: keep stale (== c2up skip)
            } else {
                float s = 0.f;
                for (int i = b; i < e; ++i) s += dotg[ord[i] * K_C + t];  // ascending
                float v = s / (float)(e - b);
                c2s[t] = v;
                if (blockIdx.x == 0) c2g[t] = v;      // persist for future empty-k reads
            }
        }
        __syncthreads();
    }
    int wid = t >> 6, lane = t & 63;
    int n = blockIdx.x * 4 + wid;
    float v = fmaf(-2.f, dotg[n * K_C + lane], c2s[lane]);
    int bi = lane;
    #pragma unroll
    for (int m = 32; m; m >>= 1) {
        float v2 = __shfl_xor(v, m);
        int   i2 = __shfl_xor(bi, m);
        if (v2 < v || (v2 == v && i2 < bi)) { v = v2; bi = i2; }
    }
    if (lane == 0) choice_it[n] = bi;
}

// ---------------- counting sort + tlast + (last-iter choice out) ----------------
__global__ __launch_bounds__(1024) void sort2_kernel(const int* __restrict__ choice,
                                                     int* __restrict__ order,
                                                     int* __restrict__ cstart,
                                                     int* __restrict__ tlast,
                                                     int it,
                                                     float* __restrict__ out_choice) {
    __shared__ int ch[N_PTS];
    __shared__ int cnt[K_C];
    __shared__ int cst[K_C + 1];
    int t = threadIdx.x;
    if (t < K_C) cnt[t] = 0;
    __syncthreads();
    int c = choice[t];
    ch[t] = c;
    atomicAdd(&cnt[c], 1);
    __syncthreads();
    if (t == 0) {
        int a = 0;
        for (int k = 0; k < K_C; ++k) { cst[k] = a; a += cnt[k]; }
        cst[K_C] = a;
    }
    __syncthreads();
    if (t <= K_C) cstart[t] = cst[t];
    if (t < K_C && cnt[t] > 0) tlast[t] = it;
    int r = 0;
    for (int m = 0; m < t; ++m) r += (ch[m] == c);
    order[cst[c] + r] = t;
    if (it == ITERS - 1) out_choice[t] = (float)c;
}

// ---------------- dot[n][k] = mean over members(k) of G[n][m] ----------------
__global__ __launch_bounds__(256) void dotup_kernel(const float* __restrict__ G,
                                                    const int* __restrict__ order,
                                                    const int* __restrict__ cstart,
                                                    float* __restrict__ dot) {
    __shared__ int ord[N_PTS];
    __shared__ int cst[K_C + 1];
    int t = threadIdx.x;
    #pragma unroll
    for (int i = 0; i < 4; ++i) ord[t + 256 * i] = order[t + 256 * i];
    if (t <= K_C) cst[t] = cstart[t];
    __syncthreads();
    int wid = t >> 6, lane = t & 63;
    int n = blockIdx.x * 4 + wid;
    int b = cst[lane], e = cst[lane + 1];
    if (b == e) return;                              // empty: keep old column
    const float* gr = G + (size_t)n * N_PTS;
    float s = 0.f;
    for (int i = b; i < e; ++i) s += gr[ord[i]];     // ascending order: deterministic
    dot[n * K_C + lane] = s / (float)(e - b);
}

// ---------------- final centroids: exact fp32 means at last-nonempty iter ----------------
__global__ __launch_bounds__(256) void final_state_kernel(const float* __restrict__ X,
                                                          const int* __restrict__ chbuf,
                                                          const int* __restrict__ tlast,
                                                          float* __restrict__ state) {
    const int k = blockIdx.x;
    const int tk = tlast[k];
    if (tk < 0) return;                              // never nonempty: keep snapped
    __shared__ int chs[N_PTS];
    const int* src = chbuf + tk * N_PTS;
    const int t = threadIdx.x;
    #pragma unroll
    for (int i = 0; i < 4; ++i) chs[t + 256 * i] = src[t + 256 * i];
    __syncthreads();
    const size_t d = (size_t)blockIdx.y * 1024 + t * 4;
    float sx = 0.f, sy = 0.f, sz = 0.f, sw = 0.f;
    int cm = 0;
    for (int n = 0; n < N_PTS; ++n) {
        if (chs[n] == k) {                           // ascending n: deterministic
            ++cm;
            const float4 v = *reinterpret_cast<const float4*>(X + (size_t)n * D_DIM + d);
            sx += v.x; sy += v.y; sz += v.z; sw += v.w;
        }
    }
    float inv = 1.f / (float)cm;
    float4 o = {sx * inv, sy * inv, sz * inv, sw * inv};
    *reinterpret_cast<float4*>(state + (size_t)k * D_DIM + d) = o;
}

extern "C" void kernel_launch(void* const* d_in, const int* in_sizes, int n_in,
                              void* d_out, int out_size, void* d_ws, size_t ws_size,
                              hipStream_t stream) {
    const float* X  = (const float*)d_in[0];
    const float* C0 = (const float*)d_in[1];
    float* state      = (float*)d_out;
    float* out_choice = state + (size_t)K_C * D_DIM;

    char* w = (char*)d_ws;
    size_t off = 0;
    auto alloc = [&](size_t bytes) { void* p = w + off; off = (off + bytes + 255) & ~(size_t)255; return p; };
    unsigned short* Xh = (unsigned short*)alloc((size_t)N_PTS * D_DIM * 2);   // 201 MB
    unsigned short* Xl = (unsigned short*)alloc((size_t)N_PTS * D_DIM * 2);   // 201 MB
    unsigned short* Sh = (unsigned short*)alloc((size_t)K_C * D_DIM * 2);     // 12.6 MB
    unsigned short* Sl = (unsigned short*)alloc((size_t)K_C * D_DIM * 2);
    float* partial = (float*)alloc((size_t)SPLITD * N_PTS * K_C * 4);         // 16 MB
    float* Gpart   = (float*)alloc((size_t)NGRP * NPAIR * GT * GT * 4);       // 37.7 MB
    float* G       = (float*)alloc((size_t)N_PTS * N_PTS * 4);                // 4 MB
    float* dotb    = (float*)alloc((size_t)N_PTS * K_C * 4);
    float* x2p     = (float*)alloc((size_t)N_PTS * CCHK * 4);
    float* x2      = (float*)alloc((size_t)N_PTS * 4);
    float* c0sq    = (float*)alloc((size_t)K_C * CCHK * 4);
    float* dotg    = (float*)alloc((size_t)N_PTS * K_C * 4);
    float* c2      = (float*)alloc(256);
    int* cpts      = (int*)alloc(256);
    int* chbuf     = (int*)alloc((size_t)ITERS * N_PTS * 4);                  // 40 KB
    int* order     = (int*)alloc((size_t)N_PTS * 4);
    int* cstart    = (int*)alloc(512);
    int* tlast     = (int*)alloc(256);

    dim3 b256(256);

    // one-time: X -> bf16 hi/lo planes + x2
    convert_kernel<<<dim3(N_PTS, CCHK), b256, 0, stream>>>(X, Xh, Xl, x2p);
    reduce_sq_kernel<<<dim3(4), b256, 0, stream>>>(x2p, x2, N_PTS);

    // G = X.X^T (3-buffer async staging, XCD-cohort)
    gbuild_kernel<<<dim3(8 * NPAIR * (NGRP / 8)), b256, 0, stream>>>(Xh, Xl, Gpart);
    reduce_g_kernel<<<dim3(NPAIR, 16), b256, 0, stream>>>(Gpart, G);

    // init ('resuming'): snap each centroid to nearest sample
    convert_kernel<<<dim3(K_C, CCHK), b256, 0, stream>>>(C0, Sh, Sl, c0sq);
    mfma_dot2_kernel<<<dim3(SPLITD, 8), b256, 0, stream>>>(Xh, Xl, Sh, Sl, partial);
    reduce_dot_kernel<<<dim3(N_PTS * K_C / 256), b256, 0, stream>>>(partial, dotb);
    argmin_n_kernel<<<K_C, b256, 0, stream>>>(dotb, x2, cpts);
    gather_kernel<<<dim3(K_C, NCHK), b256, 0, stream>>>(X, cpts, state);
    dot0_kernel<<<dim3(N_PTS * K_C / 256), b256, 0, stream>>>(G, cpts, x2, dotg, c2, tlast);

    // 10 Lloyd iterations entirely on G (3 launches/iter; last iter 2)
    for (int it = 0; it < ITERS; ++it) {
        assign_g2_kernel<<<dim3(N_PTS / 4), b256, 0, stream>>>(dotg, c2, order, cstart,
                                                               it == 0 ? 1 : 0,
                                                               chbuf + it * N_PTS);
        sort2_kernel<<<1, dim3(1024), 0, stream>>>(chbuf + it * N_PTS, order, cstart,
                                                   tlast, it, out_choice);
        if (it < ITERS - 1)
            dotup_kernel<<<dim3(N_PTS / 4), b256, 0, stream>>>(G, order, cstart, dotg);
    }

    // final: exact fp32 means using each cluster's last-nonempty choice vector
    final_state_kernel<<<dim3(K_C, NCHK), b256, 0, stream>>>(X, chbuf, tlast, state);
}

// Round 15
// 1843.520 us; speedup vs baseline: 1.0494x; 1.0494x over previous
//
#include <hip/hip_runtime.h>
#include <cstddef>
#include <cstdint>

// K-means (Lloyd, 10 fixed iters): N=1024 pts, K=64 centroids, D=98304.
// d_in[0]=x f32[1024*98304], d_in[1]=centroid f32[64*98304]
// d_out = concat(final state [64*98304] f32, last choice [1024] as f32)
//
// Round 15: clean recombination of proven-best pieces. gbuild = round 11/13
// version (2-buffer 64KB, 2 blocks/CU, counted vmcnt(8): 518us; round 14's
// 3-buffer/1-block-CU regressed 518->615 -- occupancy beats depth, third
// confirmation). Loop = round 14's trimmed structure (assign_g2 with folded
// c2up, sort2 with folded choice-out, dot0 with folded tlast-init). All
// reduction orders bit-identical (absmax 0.0 throughout).

#define N_PTS  1024
#define K_C    64
#define D_DIM  98304
#define ITERS  10
#define SPLITD 64          // init dot kernel split (1536 dims/seg)
#define NCHK   96          // D/1024
#define CCHK   12          // D/8192
#define NGRP   16          // gbuild seg-half groups
#define SHW    512         // shorts per seg-half
#define NCHT   192         // gbuild chunks per block
#define NPAIR  36          // 8x8 upper-triangle 128-tiles
#define GT     128
#define GDC    32          // dims per K-chunk

typedef __attribute__((ext_vector_type(8))) short bf16x8;
typedef __attribute__((ext_vector_type(8))) unsigned short ushort8;
typedef __attribute__((ext_vector_type(4))) float f32x4;

__device__ __forceinline__ unsigned short f2bf(float x) {   // RNE f32->bf16
    unsigned u = __float_as_uint(x);
    u = (u + 0x7FFFu + ((u >> 16) & 1u)) >> 16;
    return (unsigned short)u;
}
__device__ __forceinline__ float bf2f(unsigned short b) {
    return __uint_as_float((unsigned)b << 16);
}
__device__ __forceinline__ void cvt2(float x, unsigned short& h, unsigned short& l) {
    h = f2bf(x);
    l = f2bf(x - bf2f(h));
}

__device__ __forceinline__ void gload_lds16(const unsigned short* g, char* l) {
    __builtin_amdgcn_global_load_lds(
        (const __attribute__((address_space(1))) unsigned int*)g,
        (__attribute__((address_space(3))) unsigned int*)l, 16, 0, 0);
}

__device__ __forceinline__ float block_sum256(float s) {
    #pragma unroll
    for (int o = 32; o; o >>= 1) s += __shfl_down(s, o);
    __shared__ float red[4];
    int lane = threadIdx.x & 63, w = threadIdx.x >> 6;
    if (lane == 0) red[w] = s;
    __syncthreads();
    return red[0] + red[1] + red[2] + red[3];
}

// ---------------- convert rows fp32 -> bf16 hi/lo planes + sumsq partials ----------------
__global__ __launch_bounds__(256) void convert_kernel(const float* __restrict__ A,
                                                      unsigned short* __restrict__ Ph,
                                                      unsigned short* __restrict__ Pl,
                                                      float* __restrict__ sq_part) {
    const int n = blockIdx.x, j = blockIdx.y;
    const size_t base = (size_t)n * D_DIM + (size_t)j * 8192;
    const int t = threadIdx.x;
    float ss = 0.f;
    #pragma unroll
    for (int i = 0; i < 4; ++i) {
        size_t e = base + (size_t)i * 2048 + t * 8;
        float4 a = *reinterpret_cast<const float4*>(A + e);
        float4 b = *reinterpret_cast<const float4*>(A + e + 4);
        ss += a.x*a.x + a.y*a.y + a.z*a.z + a.w*a.w;
        ss += b.x*b.x + b.y*b.y + b.z*b.z + b.w*b.w;
        ushort4 h0, l0, h1, l1;
        cvt2(a.x, h0.x, l0.x); cvt2(a.y, h0.y, l0.y);
        cvt2(a.z, h0.z, l0.z); cvt2(a.w, h0.w, l0.w);
        cvt2(b.x, h1.x, l1.x); cvt2(b.y, h1.y, l1.y);
        cvt2(b.z, h1.z, l1.z); cvt2(b.w, h1.w, l1.w);
        *reinterpret_cast<ushort4*>(Ph + e)     = h0;
        *reinterpret_cast<ushort4*>(Ph + e + 4) = h1;
        *reinterpret_cast<ushort4*>(Pl + e)     = l0;
        *reinterpret_cast<ushort4*>(Pl + e + 4) = l1;
    }
    ss = block_sum256(ss);
    if (t == 0) sq_part[n * CCHK + j] = ss;
}

__global__ __launch_bounds__(256) void reduce_sq_kernel(const float* __restrict__ sq_part,
                                                        float* __restrict__ out, int rows) {
    int n = blockIdx.x * 256 + threadIdx.x;
    if (n >= rows) return;
    float s = 0.f;
    #pragma unroll
    for (int j = 0; j < CCHK; ++j) s += sq_part[n * CCHK + j];
    out[n] = s;
}

// ---------------- init dot vs C0: gbuild-style async dbuf engine ----------------
__global__ __launch_bounds__(256, 2) void mfma_dot2_kernel(const unsigned short* __restrict__ Xh,
                                                           const unsigned short* __restrict__ Xl,
                                                           const unsigned short* __restrict__ Sh,
                                                           const unsigned short* __restrict__ Sl,
                                                           float* __restrict__ partial) {
    __shared__ alignas(16) char L[49152];           // [buf][A 16K | B 8K]

    const int seg = blockIdx.x, nblk = blockIdx.y;
    const int t = threadIdx.x;
    const int wid = t >> 6, lane = t & 63;
    const int d_begin = seg * (D_DIM / SPLITD);     // seg * 1536
    const int NCH = (D_DIM / SPLITD) / GDC;         // 48

    const int isA = (wid < 2) ? 1 : 0;
    const int nj = isA ? 8 : 4;
    const int i0 = isA ? (wid & 1) * 8 : (wid & 1) * 4;
    const int tileoff = isA ? 0 : 16384;
    const int rowbase = isA ? nblk * 128 : 0;
    const int lw = (lane & 7) ^ (lane >> 3);
    const unsigned short* plane = isA ? ((lw & 4) ? Xl : Xh)
                                      : ((lw & 4) ? Sl : Sh);
    const unsigned short* gbase[8];
    #pragma unroll
    for (int j = 0; j < 8; ++j)
        gbase[j] = plane + (size_t)(rowbase + (i0 + j) * 8 + (lane >> 3)) * D_DIM + (lw & 3) * 8;

    const int sh = (lane >> 4) ^ (lane & 7);
    const int sl = (4 + (lane >> 4)) ^ (lane & 7);
    const int ra0 = (wid * 32 + (lane & 15)) * 128;
    const int rb0 = 16384 + (lane & 15) * 128;

    f32x4 acc[2][4];
    #pragma unroll
    for (int i = 0; i < 2; ++i)
        #pragma unroll
        for (int j = 0; j < 4; ++j) acc[i][j] = f32x4{0.f, 0.f, 0.f, 0.f};

    auto issue = [&](int idx) {
        const int d0 = d_begin + idx * GDC;
        char* dst = L + (idx & 1) * 24576 + tileoff + i0 * 1024;
        for (int j = 0; j < nj; ++j)
            gload_lds16(gbase[j] + d0, dst + j * 1024);
    };

    issue(0);
    for (int idx = 0; idx < NCH; ++idx) {
        if (idx + 1 < NCH) {
            issue(idx + 1);
            if (isA) asm volatile("s_waitcnt vmcnt(8)" ::: "memory");
            else     asm volatile("s_waitcnt vmcnt(4)" ::: "memory");
        } else {
            asm volatile("s_waitcnt vmcnt(0)" ::: "memory");
        }
        __builtin_amdgcn_s_barrier();
        __builtin_amdgcn_sched_barrier(0);
        const char* base = L + (idx & 1) * 24576;
        bf16x8 ah[2], al[2];
        #pragma unroll
        for (int fi = 0; fi < 2; ++fi) {
            ah[fi] = *reinterpret_cast<const bf16x8*>(base + ra0 + fi * 2048 + sh * 16);
            al[fi] = *reinterpret_cast<const bf16x8*>(base + ra0 + fi * 2048 + sl * 16);
        }
        #pragma unroll
        for (int fj = 0; fj < 4; ++fj) {
            bf16x8 bh = *reinterpret_cast<const bf16x8*>(base + rb0 + fj * 2048 + sh * 16);
            bf16x8 bl = *reinterpret_cast<const bf16x8*>(base + rb0 + fj * 2048 + sl * 16);
            #pragma unroll
            for (int fi = 0; fi < 2; ++fi) {
                acc[fi][fj] = __builtin_amdgcn_mfma_f32_16x16x32_bf16(ah[fi], bh, acc[fi][fj], 0, 0, 0);
                acc[fi][fj] = __builtin_amdgcn_mfma_f32_16x16x32_bf16(ah[fi], bl, acc[fi][fj], 0, 0, 0);
                acc[fi][fj] = __builtin_amdgcn_mfma_f32_16x16x32_bf16(al[fi], bh, acc[fi][fj], 0, 0, 0);
            }
        }
        __builtin_amdgcn_sched_barrier(0);
        __builtin_amdgcn_s_barrier();
    }

    #pragma unroll
    for (int fi = 0; fi < 2; ++fi)
        #pragma unroll
        for (int fj = 0; fj < 4; ++fj)
            #pragma unroll
            for (int r = 0; r < 4; ++r) {
                int n = nblk * 128 + wid * 32 + fi * 16 + (lane >> 4) * 4 + r;
                int col = fj * 16 + (lane & 15);
                partial[((size_t)seg * N_PTS + n) * K_C + col] = acc[fi][fj][r];
            }
}

__global__ __launch_bounds__(256) void reduce_dot_kernel(const float* __restrict__ partial,
                                                         float* __restrict__ dot) {
    int i = blockIdx.x * 256 + threadIdx.x;
    float s = 0.f;
    #pragma unroll 8
    for (int p = 0; p < SPLITD; ++p) s += partial[(size_t)p * N_PTS * K_C + i];
    dot[i] = s;
}

__global__ __launch_bounds__(256) void argmin_n_kernel(const float* __restrict__ dot,
                                                       const float* __restrict__ x2,
                                                       int* __restrict__ choice_pts) {
    int k = blockIdx.x;
    float best = 3.4e38f; int bi = N_PTS;
    for (int n = threadIdx.x; n < N_PTS; n += 256) {
        float v = fmaf(-2.f, dot[n * K_C + k], x2[n]);
        if (v < best || (v == best && n < bi)) { best = v; bi = n; }
    }
    #pragma unroll
    for (int off = 32; off; off >>= 1) {
        float v2 = __shfl_down(best, off);
        int   i2 = __shfl_down(bi, off);
        if (v2 < best || (v2 == best && i2 < bi)) { best = v2; bi = i2; }
    }
    __shared__ float bv[4]; __shared__ int bix[4];
    int lane = threadIdx.x & 63, wid = threadIdx.x >> 6;
    if (lane == 0) { bv[wid] = best; bix[wid] = bi; }
    __syncthreads();
    if (threadIdx.x == 0) {
        for (int w = 1; w < 4; ++w)
            if (bv[w] < best || (bv[w] == best && bix[w] < bi)) { best = bv[w]; bi = bix[w]; }
        choice_pts[k] = bi;
    }
}

// ---------------- gather snapped centroids (exact fp32) ----------------
__global__ __launch_bounds__(256) void gather_kernel(const float* __restrict__ X,
                                                     const int* __restrict__ choice_pts,
                                                     float* __restrict__ state) {
    int k = blockIdx.x;
    int c = choice_pts[k];
    size_t d = (size_t)blockIdx.y * 1024 + threadIdx.x * 4;
    float4 v = *reinterpret_cast<const float4*>(X + (size_t)c * D_DIM + d);
    *reinterpret_cast<float4*>(state + (size_t)k * D_DIM + d) = v;
}

// ---------------- G = X.X^T: dbuf async staging + counted vmcnt + cohort ----------------
// Round 11's proven config: 2 bufs x {A 16K | B 16K} = 64KB, 2 blocks/CU,
// vmcnt(8) steady state. 0 bank conflicts, 518us, absmax 0.0.
__global__ __launch_bounds__(256, 2) void gbuild_kernel(const unsigned short* __restrict__ Xh,
                                                        const unsigned short* __restrict__ Xl,
                                                        float* __restrict__ Gpart) {
    __shared__ alignas(16) char L[65536];           // [buf0: A|B][buf1: A|B]

    const int id = blockIdx.x;
    const int xr = id & 7, q = id >> 3;
    const int p = q % NPAIR;
    const int g = ((q / NPAIR) << 3) + xr;          // 0..15
    int bi = 0, rem = p, rl = 8;
    while (rem >= rl) { rem -= rl; --rl; ++bi; }
    const int bj = bi + rem;

    const int t = threadIdx.x;
    const int wid = t >> 6, lane = t & 63;
    const int wr = wid >> 1, wc = wid & 1;

    const int isA = (wid < 2) ? 1 : 0;
    const int i0 = (wid & 1) * 8;
    const int tileoff = isA ? 0 : 16384;
    const int rowbase = (isA ? bi : bj) * GT;
    const int lw = (lane & 7) ^ (lane >> 3);
    const unsigned short* plane = (lw & 4) ? Xl : Xh;
    const unsigned short* gbase[8];
    #pragma unroll
    for (int j = 0; j < 8; ++j)
        gbase[j] = plane + (size_t)(rowbase + (i0 + j) * 8 + (lane >> 3)) * D_DIM + (lw & 3) * 8;

    const int sh = (lane >> 4) ^ (lane & 7);
    const int sl = (4 + (lane >> 4)) ^ (lane & 7);
    const int ra0 = (wr * 64 + (lane & 15)) * 128;
    const int rb0 = 16384 + (wc * 64 + (lane & 15)) * 128;

    f32x4 acc[4][4];
    #pragma unroll
    for (int i = 0; i < 4; ++i)
        #pragma unroll
        for (int j = 0; j < 4; ++j) acc[i][j] = f32x4{0.f, 0.f, 0.f, 0.f};

    auto issue = [&](int idx) {
        const int d0 = (g + ((idx >> 4) << 4)) * SHW + (idx & 15) * GDC;
        char* dst = L + ((idx & 1) << 15) + tileoff + i0 * 1024;
        #pragma unroll
        for (int j = 0; j < 8; ++j)
            gload_lds16(gbase[j] + d0, dst + j * 1024);
    };

    issue(0);
    for (int idx = 0; idx < NCHT; ++idx) {
        if (idx + 1 < NCHT) {
            issue(idx + 1);
            asm volatile("s_waitcnt vmcnt(8)" ::: "memory");
        } else {
            asm volatile("s_waitcnt vmcnt(0)" ::: "memory");
        }
        __builtin_amdgcn_s_barrier();
        __builtin_amdgcn_sched_barrier(0);
        const char* base = L + ((idx & 1) << 15);
        bf16x8 ah[4], al[4];
        #pragma unroll
        for (int fi = 0; fi < 4; ++fi) {
            ah[fi] = *reinterpret_cast<const bf16x8*>(base + ra0 + fi * 2048 + sh * 16);
            al[fi] = *reinterpret_cast<const bf16x8*>(base + ra0 + fi * 2048 + sl * 16);
        }
        #pragma unroll
        for (int fj = 0; fj < 4; ++fj) {
            bf16x8 bh = *reinterpret_cast<const bf16x8*>(base + rb0 + fj * 2048 + sh * 16);
            bf16x8 bl = *reinterpret_cast<const bf16x8*>(base + rb0 + fj * 2048 + sl * 16);
            #pragma unroll
            for (int fi = 0; fi < 4; ++fi) {
                acc[fi][fj] = __builtin_amdgcn_mfma_f32_16x16x32_bf16(ah[fi], bh, acc[fi][fj], 0, 0, 0);
                acc[fi][fj] = __builtin_amdgcn_mfma_f32_16x16x32_bf16(ah[fi], bl, acc[fi][fj], 0, 0, 0);
                acc[fi][fj] = __builtin_amdgcn_mfma_f32_16x16x32_bf16(al[fi], bh, acc[fi][fj], 0, 0, 0);
            }
        }
        __builtin_amdgcn_sched_barrier(0);
        __builtin_amdgcn_s_barrier();
    }

    float* gp = Gpart + ((size_t)g * NPAIR + p) * (GT * GT);
    #pragma unroll
    for (int fi = 0; fi < 4; ++fi)
        #pragma unroll
        for (int fj = 0; fj < 4; ++fj)
            #pragma unroll
            for (int r2 = 0; r2 < 4; ++r2) {
                int row = wr * 64 + fi * 16 + (lane >> 4) * 4 + r2;
                int col = wc * 64 + fj * 16 + (lane & 15);
                gp[row * GT + col] = acc[fi][fj][r2];
            }
}

// ---------------- reduce G partials over groups + mirror to lower triangle ----------------
__global__ __launch_bounds__(256) void reduce_g_kernel(const float* __restrict__ Gpart,
                                                       float* __restrict__ G) {
    const int p = blockIdx.x, blk = blockIdx.y;     // grid (NPAIR, 16)
    int bi = 0, rem = p, rl = 8;
    while (rem >= rl) { rem -= rl; --rl; ++bi; }
    const int bj = bi + rem;
    const int e0 = blk * 1024 + threadIdx.x * 4;
    float sx = 0.f, sy = 0.f, sz = 0.f, sw = 0.f;
    #pragma unroll 8
    for (int g = 0; g < NGRP; ++g) {
        const float4 v = *reinterpret_cast<const float4*>(
            Gpart + ((size_t)g * NPAIR + p) * (GT * GT) + e0);
        sx += v.x; sy += v.y; sz += v.z; sw += v.w;
    }
    const int row = e0 >> 7, col = e0 & 127;
    const int gi = bi * GT + row, gj = bj * GT + col;
    float4 o = {sx, sy, sz, sw};
    *reinterpret_cast<float4*>(&G[(size_t)gi * N_PTS + gj]) = o;
    if (bi != bj) {                                 // mirror (single writer per elem)
        G[(size_t)(gj + 0) * N_PTS + gi] = sx;
        G[(size_t)(gj + 1) * N_PTS + gi] = sy;
        G[(size_t)(gj + 2) * N_PTS + gi] = sz;
        G[(size_t)(gj + 3) * N_PTS + gi] = sw;
    }
}

// ---------------- dot0 + tlast init ----------------
__global__ __launch_bounds__(256) void dot0_kernel(const float* __restrict__ G,
                                                   const int* __restrict__ cpts,
                                                   const float* __restrict__ x2,
                                                   float* __restrict__ dot,
                                                   float* __restrict__ c2,
                                                   int* __restrict__ tlast) {
    int g = blockIdx.x * 256 + threadIdx.x;
    int n = g >> 6, k = g & 63;
    dot[g] = G[(size_t)n * N_PTS + cpts[k]];
    if (g < K_C) { c2[g] = x2[cpts[g]]; tlast[g] = -1; }
}

// ---------------- assign (+ folded c2 recompute, == c2up serial order) ----------------
__global__ __launch_bounds__(256) void assign_g2_kernel(const float* __restrict__ dotg,
                                                        float* __restrict__ c2g,
                                                        const int* __restrict__ order,
                                                        const int* __restrict__ cstart,
                                                        int it0,
                                                        int* __restrict__ choice_it) {
    __shared__ float c2s[K_C];
    __shared__ int cst[K_C + 1];
    __shared__ int ord[N_PTS];
    int t = threadIdx.x;
    if (it0) {
        if (t < K_C) c2s[t] = c2g[t];
        __syncthreads();
    } else {
        #pragma unroll
        for (int i = 0; i < 4; ++i) ord[t + 256 * i] = order[t + 256 * i];
        if (t <= K_C) cst[t] = cstart[t];
        __syncthreads();
        if (t < K_C) {
            int b = cst[t], e = cst[t + 1];
            if (b == e) {
                c2s[t] = c2g[t];                      // empty: keep stale (== c2up skip)
            } else {
                float s = 0.f;
                for (int i = b; i < e; ++i) s += dotg[ord[i] * K_C + t];  // ascending
                float v = s / (float)(e - b);
                c2s[t] = v;
                if (blockIdx.x == 0) c2g[t] = v;      // persist for future empty-k reads
            }
        }
        __syncthreads();
    }
    int wid = t >> 6, lane = t & 63;
    int n = blockIdx.x * 4 + wid;
    float v = fmaf(-2.f, dotg[n * K_C + lane], c2s[lane]);
    int bi = lane;
    #pragma unroll
    for (int m = 32; m; m >>= 1) {
        float v2 = __shfl_xor(v, m);
        int   i2 = __shfl_xor(bi, m);
        if (v2 < v || (v2 == v && i2 < bi)) { v = v2; bi = i2; }
    }
    if (lane == 0) choice_it[n] = bi;
}

// ---------------- counting sort + tlast + (last-iter choice out) ----------------
__global__ __launch_bounds__(1024) void sort2_kernel(const int* __restrict__ choice,
                                                     int* __restrict__ order,
                                                     int* __restrict__ cstart,
                                                     int* __restrict__ tlast,
                                                     int it,
                                                     float* __restrict__ out_choice) {
    __shared__ int ch[N_PTS];
    __shared__ int cnt[K_C];
    __shared__ int cst[K_C + 1];
    int t = threadIdx.x;
    if (t < K_C) cnt[t] = 0;
    __syncthreads();
    int c = choice[t];
    ch[t] = c;
    atomicAdd(&cnt[c], 1);
    __syncthreads();
    if (t == 0) {
        int a = 0;
        for (int k = 0; k < K_C; ++k) { cst[k] = a; a += cnt[k]; }
        cst[K_C] = a;
    }
    __syncthreads();
    if (t <= K_C) cstart[t] = cst[t];
    if (t < K_C && cnt[t] > 0) tlast[t] = it;
    int r = 0;
    for (int m = 0; m < t; ++m) r += (ch[m] == c);
    order[cst[c] + r] = t;
    if (it == ITERS - 1) out_choice[t] = (float)c;
}

// ---------------- dot[n][k] = mean over members(k) of G[n][m] ----------------
__global__ __launch_bounds__(256) void dotup_kernel(const float* __restrict__ G,
                                                    const int* __restrict__ order,
                                                    const int* __restrict__ cstart,
                                                    float* __restrict__ dot) {
    __shared__ int ord[N_PTS];
    __shared__ int cst[K_C + 1];
    int t = threadIdx.x;
    #pragma unroll
    for (int i = 0; i < 4; ++i) ord[t + 256 * i] = order[t + 256 * i];
    if (t <= K_C) cst[t] = cstart[t];
    __syncthreads();
    int wid = t >> 6, lane = t & 63;
    int n = blockIdx.x * 4 + wid;
    int b = cst[lane], e = cst[lane + 1];
    if (b == e) return;                              // empty: keep old column
    const float* gr = G + (size_t)n * N_PTS;
    float s = 0.f;
    for (int i = b; i < e; ++i) s += gr[ord[i]];     // ascending order: deterministic
    dot[n * K_C + lane] = s / (float)(e - b);
}

// ---------------- final centroids: exact fp32 means at last-nonempty iter ----------------
__global__ __launch_bounds__(256) void final_state_kernel(const float* __restrict__ X,
                                                          const int* __restrict__ chbuf,
                                                          const int* __restrict__ tlast,
                                                          float* __restrict__ state) {
    const int k = blockIdx.x;
    const int tk = tlast[k];
    if (tk < 0) return;                              // never nonempty: keep snapped
    __shared__ int chs[N_PTS];
    const int* src = chbuf + tk * N_PTS;
    const int t = threadIdx.x;
    #pragma unroll
    for (int i = 0; i < 4; ++i) chs[t + 256 * i] = src[t + 256 * i];
    __syncthreads();
    const size_t d = (size_t)blockIdx.y * 1024 + t * 4;
    float sx = 0.f, sy = 0.f, sz = 0.f, sw = 0.f;
    int cm = 0;
    for (int n = 0; n < N_PTS; ++n) {
        if (chs[n] == k) {                           // ascending n: deterministic
            ++cm;
            const float4 v = *reinterpret_cast<const float4*>(X + (size_t)n * D_DIM + d);
            sx += v.x; sy += v.y; sz += v.z; sw += v.w;
        }
    }
    float inv = 1.f / (float)cm;
    float4 o = {sx * inv, sy * inv, sz * inv, sw * inv};
    *reinterpret_cast<float4*>(state + (size_t)k * D_DIM + d) = o;
}

extern "C" void kernel_launch(void* const* d_in, const int* in_sizes, int n_in,
                              void* d_out, int out_size, void* d_ws, size_t ws_size,
                              hipStream_t stream) {
    const float* X  = (const float*)d_in[0];
    const float* C0 = (const float*)d_in[1];
    float* state      = (float*)d_out;
    float* out_choice = state + (size_t)K_C * D_DIM;

    char* w = (char*)d_ws;
    size_t off = 0;
    auto alloc = [&](size_t bytes) { void* p = w + off; off = (off + bytes + 255) & ~(size_t)255; return p; };
    unsigned short* Xh = (unsigned short*)alloc((size_t)N_PTS * D_DIM * 2);   // 201 MB
    unsigned short* Xl = (unsigned short*)alloc((size_t)N_PTS * D_DIM * 2);   // 201 MB
    unsigned short* Sh = (unsigned short*)alloc((size_t)K_C * D_DIM * 2);     // 12.6 MB
    unsigned short* Sl = (unsigned short*)alloc((size_t)K_C * D_DIM * 2);
    float* partial = (float*)alloc((size_t)SPLITD * N_PTS * K_C * 4);         // 16 MB
    float* Gpart   = (float*)alloc((size_t)NGRP * NPAIR * GT * GT * 4);       // 37.7 MB
    float* G       = (float*)alloc((size_t)N_PTS * N_PTS * 4);                // 4 MB
    float* dotb    = (float*)alloc((size_t)N_PTS * K_C * 4);
    float* x2p     = (float*)alloc((size_t)N_PTS * CCHK * 4);
    float* x2      = (float*)alloc((size_t)N_PTS * 4);
    float* c0sq    = (float*)alloc((size_t)K_C * CCHK * 4);
    float* dotg    = (float*)alloc((size_t)N_PTS * K_C * 4);
    float* c2      = (float*)alloc(256);
    int* cpts      = (int*)alloc(256);
    int* chbuf     = (int*)alloc((size_t)ITERS * N_PTS * 4);                  // 40 KB
    int* order     = (int*)alloc((size_t)N_PTS * 4);
    int* cstart    = (int*)alloc(512);
    int* tlast     = (int*)alloc(256);

    dim3 b256(256);

    // one-time: X -> bf16 hi/lo planes + x2
    convert_kernel<<<dim3(N_PTS, CCHK), b256, 0, stream>>>(X, Xh, Xl, x2p);
    reduce_sq_kernel<<<dim3(4), b256, 0, stream>>>(x2p, x2, N_PTS);

    // G = X.X^T (2-buffer async staging, XCD-cohort)
    gbuild_kernel<<<dim3(8 * NPAIR * (NGRP / 8)), b256, 0, stream>>>(Xh, Xl, Gpart);
    reduce_g_kernel<<<dim3(NPAIR, 16), b256, 0, stream>>>(Gpart, G);

    // init ('resuming'): snap each centroid to nearest sample
    convert_kernel<<<dim3(K_C, CCHK), b256, 0, stream>>>(C0, Sh, Sl, c0sq);
    mfma_dot2_kernel<<<dim3(SPLITD, 8), b256, 0, stream>>>(Xh, Xl, Sh, Sl, partial);
    reduce_dot_kernel<<<dim3(N_PTS * K_C / 256), b256, 0, stream>>>(partial, dotb);
    argmin_n_kernel<<<K_C, b256, 0, stream>>>(dotb, x2, cpts);
    gather_kernel<<<dim3(K_C, NCHK), b256, 0, stream>>>(X, cpts, state);
    dot0_kernel<<<dim3(N_PTS * K_C / 256), b256, 0, stream>>>(G, cpts, x2, dotg, c2, tlast);

    // 10 Lloyd iterations entirely on G (3 launches/iter; last iter 2)
    for (int it = 0; it < ITERS; ++it) {
        assign_g2_kernel<<<dim3(N_PTS / 4), b256, 0, stream>>>(dotg, c2, order, cstart,
                                                               it == 0 ? 1 : 0,
                                                               chbuf + it * N_PTS);
        sort2_kernel<<<1, dim3(1024), 0, stream>>>(chbuf + it * N_PTS, order, cstart,
                                                   tlast, it, out_choice);
        if (it < ITERS - 1)
            dotup_kernel<<<dim3(N_PTS / 4), b256, 0, stream>>>(G, order, cstart, dotg);
    }

    // final: exact fp32 means using each cluster's last-nonempty choice vector
    final_state_kernel<<<dim3(K_C, NCHK), b256, 0, stream>>>(X, chbuf, tlast, state);
}